// Round 11
// baseline (167.617 us; speedup 1.0000x reference)
//
#include <hip/hip_runtime.h>
#include <stdint.h>

#define HID 64
#define RPB 128          // rows per dst bin
#define NBB 512          // blocks for hist/binscat streaming passes
#define MAXBINS 2048     // need 2*NBF <= MAXBINS

typedef __attribute__((ext_vector_type(8))) short bf16x8;
typedef __attribute__((ext_vector_type(4))) float f32x4;

// ---------------------------------------------------------------------------
// bf16 helpers (RTNE pack, cheap unpack).
__device__ inline float bf2f(unsigned short u) {
  return __uint_as_float(((unsigned)u) << 16);
}
__device__ inline unsigned short f2bf(float f) {
  unsigned u = __float_as_uint(f);
  unsigned r = u + 0x7FFFu + ((u >> 16) & 1u);
  return (unsigned short)(r >> 16);
}
__device__ inline unsigned pk2(float a, float b) {
  return (unsigned)f2bf(a) | ((unsigned)f2bf(b) << 16);
}

// ---------------------------------------------------------------------------
// Mbt = bf16, transposed fused weights; cvec = fused bias. Block 16 detects
// edge dtype (int64 vs int32) from high words of the first 1024 values.
__global__ __launch_bounds__(256) void k_prep(
    const float* __restrict__ Wpos, const float* __restrict__ Wneg,
    const float* __restrict__ Wp, const float* __restrict__ Wn,
    const float* __restrict__ bpos, const float* __restrict__ bneg,
    const float* __restrict__ bp, const float* __restrict__ bn,
    unsigned short* __restrict__ Mbt, float* __restrict__ cvec,
    const unsigned* __restrict__ eiw, unsigned* __restrict__ flag, int nWords) {
  if (blockIdx.x == 16) {
    __shared__ unsigned acc;
    if (threadIdx.x == 0) acc = 0u;
    __syncthreads();
    unsigned bad = 0u;
    for (int i = 0; i < 4; ++i) {
      int w = (i * 256 + (int)threadIdx.x) * 2 + 1;
      if (w < nWords) bad |= eiw[w];
    }
    if (bad) atomicOr(&acc, 1u);
    __syncthreads();
    if (threadIdx.x == 0) *flag = (acc == 0u) ? 1u : 0u;  // 1 => int64
    return;
  }
  int idx = blockIdx.x * 256 + threadIdx.x;
  int i = idx >> 6, j = idx & 63;   // i = k (LN dim), j = output col
  float a = 0.f, b = 0.f;
  for (int k = 0; k < 64; ++k) {
    a += Wpos[i * 64 + k] * Wp[k * 64 + j];
    b += Wneg[i * 64 + k] * Wn[k * 64 + j];
  }
  Mbt[j * 64 + i] = f2bf(a);
  Mbt[(64 + j) * 64 + i] = f2bf(b);
  if (blockIdx.x == 0 && threadIdx.x < 64) {
    int jj = threadIdx.x;
    float acc = bp[jj] + bn[jj];
    for (int k = 0; k < 64; ++k)
      acc += bpos[k] * Wp[k * 64 + jj] + bneg[k] * Wn[k * 64 + jj];
    cvec[jj] = acc;
  }
}

// ---------------------------------------------------------------------------
// Pass 1: per-block LDS histogram of dst bins. histG layout: [bin][block].
__global__ __launch_bounds__(256) void k_hist(
    const void* __restrict__ eip, const void* __restrict__ ein,
    const unsigned* __restrict__ flag, unsigned* __restrict__ histG,
    int Ep, int En, int NBF, long long chunk) {
  __shared__ unsigned hist[MAXBINS];
  const int nbins = 2 * NBF;
  for (int i = threadIdx.x; i < nbins; i += 256) hist[i] = 0u;
  __syncthreads();
  const long long ET = (long long)Ep + En;
  long long beg = (long long)blockIdx.x * chunk;
  long long end = beg + chunk;
  if (end > ET) end = ET;
  const bool is64 = (*flag != 0u);
  for (long long e = beg + threadIdx.x; e < end; e += 256) {
    int seg = e >= Ep;
    long long ee = seg ? e - Ep : e;
    const void* ei = seg ? ein : eip;
    long long Ecur = seg ? En : Ep;
    int d;
    if (is64) d = (int)((const long long*)ei)[Ecur + ee];
    else      d = ((const int*)ei)[Ecur + ee];
    atomicAdd(&hist[seg * NBF + (d >> 7)], 1u);
  }
  __syncthreads();
  for (int i = threadIdx.x; i < nbins; i += 256)
    histG[(size_t)i * NBB + blockIdx.x] = hist[i];
}

// ---------------------------------------------------------------------------
// Pass 2a: one wave per bin — exclusive prefix across blocks, emit totals.
__global__ __launch_bounds__(256) void k_scanA(unsigned* __restrict__ histG,
                                               unsigned* __restrict__ binTot,
                                               int nbins) {
  const int w = threadIdx.x >> 6, lane = threadIdx.x & 63;
  const int b = blockIdx.x * 4 + w;
  if (b >= nbins) return;
  unsigned* row = histG + (size_t)b * NBB;
  unsigned carry = 0u;
  for (int c = 0; c < NBB; c += 64) {
    unsigned v = row[c + lane];
    unsigned incl = v;
#pragma unroll
    for (int o = 1; o < 64; o <<= 1) {
      unsigned x = __shfl_up(incl, o);
      if (lane >= o) incl += x;
    }
    row[c + lane] = incl - v + carry;
    carry += __shfl(incl, 63);
  }
  if (lane == 0) binTot[b] = carry;
}

// Pass 2b: single block — exclusive scan of bin totals -> offsB.
__global__ __launch_bounds__(256) void k_scanB(const unsigned* __restrict__ binTot,
                                               unsigned* __restrict__ offsB,
                                               int nbins, long long ET) {
  __shared__ unsigned sh[MAXBINS];
  const int t = threadIdx.x;
  for (int i = t; i < MAXBINS; i += 256) sh[i] = (i < nbins) ? binTot[i] : 0u;
  __syncthreads();
  for (int off = 1; off < MAXBINS; off <<= 1) {
    unsigned v[MAXBINS / 256];
#pragma unroll
    for (int k = 0; k < MAXBINS / 256; ++k) {
      int i = t + k * 256;
      v[k] = (i >= off) ? sh[i - off] : 0u;
    }
    __syncthreads();
#pragma unroll
    for (int k = 0; k < MAXBINS / 256; ++k) sh[t + k * 256] += v[k];
    __syncthreads();
  }
  for (int i = t; i < nbins; i += 256) offsB[i] = (i == 0) ? 0u : sh[i - 1];
  if (t == 0) offsB[nbins] = (unsigned)ET;
}

// ---------------------------------------------------------------------------
// Pass 3: scatter packed records src|(dlocal<<20) into per-(block,bin)
// sequential runs.
__global__ __launch_bounds__(256) void k_binscat(
    const void* __restrict__ eip, const void* __restrict__ ein,
    const unsigned* __restrict__ flag, const unsigned* __restrict__ histG,
    const unsigned* __restrict__ offsB, unsigned* __restrict__ binned,
    int Ep, int En, int NBF, long long chunk) {
  __shared__ unsigned cur[MAXBINS];
  const int nbins = 2 * NBF;
  for (int i = threadIdx.x; i < nbins; i += 256)
    cur[i] = histG[(size_t)i * NBB + blockIdx.x] + offsB[i];
  __syncthreads();
  const long long ET = (long long)Ep + En;
  long long beg = (long long)blockIdx.x * chunk;
  long long end = beg + chunk;
  if (end > ET) end = ET;
  const bool is64 = (*flag != 0u);
  for (long long e = beg + threadIdx.x; e < end; e += 256) {
    int seg = e >= Ep;
    long long ee = seg ? e - Ep : e;
    const void* ei = seg ? ein : eip;
    long long Ecur = seg ? En : Ep;
    int s, d;
    if (is64) {
      const long long* p = (const long long*)ei;
      s = (int)p[ee]; d = (int)p[Ecur + ee];
    } else {
      const int* p = (const int*)ei;
      s = p[ee]; d = p[Ecur + ee];
    }
    unsigned pos = atomicAdd(&cur[seg * NBF + (d >> 7)], 1u);
    binned[pos] = (unsigned)s | ((unsigned)(d & 127) << 20);
  }
}

// ---------------------------------------------------------------------------
// Pass 4: one block per bin — counting-sort by dlocal -> per-node CSR,
// offs + dinv.
__global__ __launch_bounds__(256) void k_binsort(
    const unsigned* __restrict__ binned, const unsigned* __restrict__ offsB,
    unsigned* __restrict__ csr, unsigned* __restrict__ offsp,
    unsigned* __restrict__ offsn, float* __restrict__ dinvp,
    float* __restrict__ dinvn, int N, int NBF) {
  __shared__ unsigned cnt[RPB], sc[RPB], cur[RPB];
  const int t = threadIdx.x;
  const int b = blockIdx.x;
  for (int seg = 0; seg < 2; ++seg) {
    const unsigned sb = offsB[seg * NBF + b];
    const unsigned se = offsB[seg * NBF + b + 1];
    if (t < RPB) cnt[t] = 0u;
    __syncthreads();
    for (unsigned i = sb + t; i < se; i += 256)
      atomicAdd(&cnt[binned[i] >> 20], 1u);
    __syncthreads();
    if (t < RPB) sc[t] = cnt[t];
    __syncthreads();
#pragma unroll
    for (int o = 1; o < RPB; o <<= 1) {
      unsigned v = 0u;
      if (t < RPB && t >= o) v = sc[t - o];
      __syncthreads();
      if (t < RPB) sc[t] += v;
      __syncthreads();
    }
    if (t < RPB) {
      unsigned excl = sc[t] - cnt[t];
      cur[t] = sb + excl;
      int g = b * RPB + t;
      if (g < N) {
        if (seg == 0) {
          offsp[g] = sb + excl;
          dinvp[g] = rsqrtf((float)cnt[t] + 1.0f);
        } else {
          offsn[g] = sb + excl;
          dinvn[g] = rsqrtf((float)cnt[t] + 1.0f);
        }
      }
    }
    __syncthreads();
    for (unsigned i = sb + t; i < se; i += 256) {
      unsigned w = binned[i];
      unsigned p = atomicAdd(&cur[w >> 20], 1u);
      csr[p] = w & 0xFFFFFu;
    }
    __syncthreads();
  }
  if (b == 0 && t == 0) {
    offsp[N] = offsB[NBF];
    offsn[N] = offsB[2 * NBF];
  }
}

// ---------------------------------------------------------------------------
// Fused LayerNorm + dual GEMM via MFMA (bf16 in, fp32 acc), epilogue scales by
// dinv[row], stores bf16. Block = 256 threads = 4 waves, 64 rows.
__global__ __launch_bounds__(256) void k_ln_gemm(
    const float* __restrict__ h, const float* __restrict__ gamma,
    const float* __restrict__ beta, const unsigned short* __restrict__ Mbt,
    const float* __restrict__ dinvp, const float* __restrict__ dinvn,
    unsigned short* __restrict__ yp, unsigned short* __restrict__ yn, int N) {
  __shared__ __align__(16) unsigned short Abf[64][72];
  __shared__ __align__(16) unsigned short Bt[128][72];
  const int t = threadIdx.x;
  const int r0 = blockIdx.x * 64;

  // Stage B: 128 rows x 64 bf16 = 1024 uint4; 4 uint4 per thread.
#pragma unroll
  for (int i = 0; i < 4; ++i) {
    int f = i * 256 + t;
    int n = f >> 3, c8 = f & 7;
    *(uint4*)(&Bt[n][c8 * 8]) = ((const uint4*)Mbt)[f];
  }

  // LayerNorm: thread (r = t>>2, p = t&3) handles 16 cols of row r0+r.
  const int r = t >> 2, p = t & 3;
  float4 va, vb, vc, vd;
  if (r0 + r < N) {
    const float4* hp = (const float4*)(h + (size_t)(r0 + r) * 64 + p * 16);
    va = hp[0]; vb = hp[1]; vc = hp[2]; vd = hp[3];
  } else {
    va = vb = vc = vd = make_float4(0.f, 0.f, 0.f, 0.f);
  }
  float s  = (va.x + va.y + va.z + va.w) + (vb.x + vb.y + vb.z + vb.w) +
             (vc.x + vc.y + vc.z + vc.w) + (vd.x + vd.y + vd.z + vd.w);
  float ss = (va.x*va.x + va.y*va.y + va.z*va.z + va.w*va.w) +
             (vb.x*vb.x + vb.y*vb.y + vb.z*vb.z + vb.w*vb.w) +
             (vc.x*vc.x + vc.y*vc.y + vc.z*vc.z + vc.w*vc.w) +
             (vd.x*vd.x + vd.y*vd.y + vd.z*vd.z + vd.w*vd.w);
  s  += __shfl_xor(s, 1);  ss += __shfl_xor(ss, 1);
  s  += __shfl_xor(s, 2);  ss += __shfl_xor(ss, 2);
  float mu = s * (1.f / 64.f);
  float var = ss * (1.f / 64.f) - mu * mu;
  float rstd = rsqrtf(var + 1e-5f);
  {
    const float4* g4 = (const float4*)(gamma + p * 16);
    const float4* b4 = (const float4*)(beta + p * 16);
    float4 g0 = g4[0], g1 = g4[1], g2 = g4[2], g3 = g4[3];
    float4 e0 = b4[0], e1 = b4[1], e2 = b4[2], e3 = b4[3];
#define LNV(v, g, e) ((v - mu) * rstd * g + e)
    unsigned w0 = pk2(LNV(va.x, g0.x, e0.x), LNV(va.y, g0.y, e0.y));
    unsigned w1 = pk2(LNV(va.z, g0.z, e0.z), LNV(va.w, g0.w, e0.w));
    unsigned w2 = pk2(LNV(vb.x, g1.x, e1.x), LNV(vb.y, g1.y, e1.y));
    unsigned w3 = pk2(LNV(vb.z, g1.z, e1.z), LNV(vb.w, g1.w, e1.w));
    unsigned w4 = pk2(LNV(vc.x, g2.x, e2.x), LNV(vc.y, g2.y, e2.y));
    unsigned w5 = pk2(LNV(vc.z, g2.z, e2.z), LNV(vc.w, g2.w, e2.w));
    unsigned w6 = pk2(LNV(vd.x, g3.x, e3.x), LNV(vd.y, g3.y, e3.y));
    unsigned w7 = pk2(LNV(vd.z, g3.z, e3.z), LNV(vd.w, g3.w, e3.w));
#undef LNV
    *(uint4*)(&Abf[r][p * 16]) = make_uint4(w0, w1, w2, w3);
    *(uint4*)(&Abf[r][p * 16 + 8]) = make_uint4(w4, w5, w6, w7);
  }
  __syncthreads();

  // MFMA phase.
  const int w = t >> 6, lane = t & 63;
  const int mrow = lane & 15, grp = lane >> 4;
  bf16x8 a0 = *(const bf16x8*)(&Abf[w * 16 + mrow][grp * 8]);
  bf16x8 a1 = *(const bf16x8*)(&Abf[w * 16 + mrow][32 + grp * 8]);
  float sp[4], sn[4];
#pragma unroll
  for (int reg = 0; reg < 4; ++reg) {
    int grow = r0 + w * 16 + grp * 4 + reg;
    sp[reg] = (grow < N) ? dinvp[grow] : 0.f;
    sn[reg] = (grow < N) ? dinvn[grow] : 0.f;
  }
#pragma unroll
  for (int ct = 0; ct < 8; ++ct) {
    const int n = ct * 16 + mrow;
    bf16x8 b0 = *(const bf16x8*)(&Bt[n][grp * 8]);
    bf16x8 b1 = *(const bf16x8*)(&Bt[n][32 + grp * 8]);
    f32x4 acc = {0.f, 0.f, 0.f, 0.f};
    acc = __builtin_amdgcn_mfma_f32_16x16x32_bf16(a0, b0, acc, 0, 0, 0);
    acc = __builtin_amdgcn_mfma_f32_16x16x32_bf16(a1, b1, acc, 0, 0, 0);
#pragma unroll
    for (int reg = 0; reg < 4; ++reg) {
      int grow = r0 + w * 16 + grp * 4 + reg;
      if (grow < N) {
        if (ct < 4)
          yp[(size_t)grow * 64 + ct * 16 + mrow] = f2bf(sp[reg] * acc[reg]);
        else
          yn[(size_t)grow * 64 + (ct - 4) * 16 + mrow] = f2bf(sn[reg] * acc[reg]);
      }
    }
  }
}

// ---------------------------------------------------------------------------
// Phase gather: one wave per dst node, ONE edge set per kernel (halves the
// instantaneous random working set: one 25.6 MB y array instead of two).
// Round-9-proven inner loop: FOUR 16-lane groups, uint2/lane, 2-deep unroll
// (8 rows in flight). All __shfl execute wave-uniformly with clamped source
// index (ds_bpermute from EXEC-inactive source lane is undefined).
// PHASE 0: out = cvec + dinv[d]*acc (no clip).
// PHASE 1: out += dinv[d]*acc, then clip.
template <int PHASE>
__global__ __launch_bounds__(256) void k_gather1(
    const unsigned* __restrict__ offs, const unsigned* __restrict__ csr,
    const float* __restrict__ dinv, const unsigned short* __restrict__ y,
    const float* __restrict__ cvec, float* __restrict__ out, int N) {
  const int lane = threadIdx.x & 63;
  const int grp = lane >> 4;     // 0..3
  const int lc = lane & 15;      // column group: cols lc*4..lc*4+3
  const int d = (int)(((long long)blockIdx.x * 256 + threadIdx.x) >> 6);
  if (d >= N) return;

  float4 a = make_float4(0.f, 0.f, 0.f, 0.f);

#define ACC4(ACC, U)                                                         \
  ACC.x += bf2f((unsigned short)(U.x & 0xFFFFu));                            \
  ACC.y += bf2f((unsigned short)(U.x >> 16));                                \
  ACC.z += bf2f((unsigned short)(U.y & 0xFFFFu));                            \
  ACC.w += bf2f((unsigned short)(U.y >> 16));

  {
    unsigned beg = offs[d], end = offs[d + 1];
    for (unsigned base = beg; base < end; base += 64u) {
      int m = (int)min(64u, end - base);
      int idx = (base + (unsigned)lane < end) ? (int)csr[base + lane] : 0;
      int j = 0;
      for (; j + 7 < m; j += 8) {
        int s0 = __shfl(idx, j + grp);
        int s1 = __shfl(idx, j + 4 + grp);
        uint2 u0 = *(const uint2*)(y + (size_t)s0 * 64 + 4 * lc);
        uint2 u1 = *(const uint2*)(y + (size_t)s1 * 64 + 4 * lc);
        ACC4(a, u0)
        ACC4(a, u1)
      }
      for (; j < m; j += 4) {
        int e = j + grp;
        int es = (e < m) ? e : (m - 1);  // clamp: source lane stays valid
        int s0 = __shfl(idx, es);        // executed by ALL lanes
        if (e < m) {
          uint2 u0 = *(const uint2*)(y + (size_t)s0 * 64 + 4 * lc);
          ACC4(a, u0)
        }
      }
    }
  }

  // Combine the 4 groups (butterfly over fully-active wave).
  a.x += __shfl_xor(a.x, 16); a.y += __shfl_xor(a.y, 16);
  a.z += __shfl_xor(a.z, 16); a.w += __shfl_xor(a.w, 16);
  a.x += __shfl_xor(a.x, 32); a.y += __shfl_xor(a.y, 32);
  a.z += __shfl_xor(a.z, 32); a.w += __shfl_xor(a.w, 32);

  if (lane < 16) {
    // Self-loop row (counted once).
    uint2 u = *(const uint2*)(y + (size_t)d * 64 + 4 * lc);
    ACC4(a, u)
    float dv = dinv[d];
    float4 v;
    if (PHASE == 0) {
      float4 cc = *(const float4*)(cvec + 4 * lc);
      v.x = cc.x + dv * a.x;
      v.y = cc.y + dv * a.y;
      v.z = cc.z + dv * a.z;
      v.w = cc.w + dv * a.w;
    } else {
      float4 prev = *(const float4*)(out + (size_t)d * 64 + 4 * lc);
      v.x = fminf(fmaxf(prev.x + dv * a.x, -50.f), 50.f);
      v.y = fminf(fmaxf(prev.y + dv * a.y, -50.f), 50.f);
      v.z = fminf(fmaxf(prev.z + dv * a.z, -50.f), 50.f);
      v.w = fminf(fmaxf(prev.w + dv * a.w, -50.f), 50.f);
    }
    *(float4*)(out + (size_t)d * 64 + 4 * lc) = v;
  }
#undef ACC4
}

// ---------------------------------------------------------------------------
// Fallback path (atomic scatter), bf16 y pre-scaled by dinv[src].
__global__ __launch_bounds__(256) void k_deg(const void* __restrict__ ei,
                                             const unsigned* __restrict__ flag,
                                             float* __restrict__ deg, int E) {
  int e = blockIdx.x * 256 + threadIdx.x;
  if (e >= E) return;
  long long d;
  if (*flag) d = ((const long long*)ei)[(long long)E + e];
  else       d = (long long)((const int*)ei)[(long long)E + e];
  atomicAdd(&deg[(int)d], 1.0f);
}

__global__ __launch_bounds__(256) void k_dinv(float* __restrict__ degp,
                                              float* __restrict__ degn, int N) {
  int i = blockIdx.x * 256 + threadIdx.x;
  if (i < N) {
    degp[i] = rsqrtf(degp[i] + 1.0f);
    degn[i] = rsqrtf(degn[i] + 1.0f);
  }
}

__global__ __launch_bounds__(256) void k_init_out(
    const unsigned short* __restrict__ yp, const unsigned short* __restrict__ yn,
    const float* __restrict__ dinvp, const float* __restrict__ dinvn,
    const float* __restrict__ cvec, float* __restrict__ out, long long n) {
  long long i = (long long)blockIdx.x * 256 + threadIdx.x;
  if (i >= n) return;
  int row = (int)(i >> 6), col = (int)(i & 63);
  out[i] = cvec[col] + dinvp[row] * bf2f(yp[i]) + dinvn[row] * bf2f(yn[i]);
}

__global__ __launch_bounds__(256) void k_scatter(
    const void* __restrict__ ei, const unsigned* __restrict__ flag,
    const float* __restrict__ dinv, const unsigned short* __restrict__ y,
    float* __restrict__ out, int E) {
  const int lane = threadIdx.x & 63;
  long long e = ((long long)blockIdx.x * 256 + threadIdx.x) >> 6;
  if (e >= E) return;
  long long s, d;
  if (*flag) {
    const long long* p = (const long long*)ei;
    s = p[e]; d = p[E + e];
  } else {
    const int* p = (const int*)ei;
    s = (long long)p[e]; d = (long long)p[E + e];
  }
  float v = dinv[(int)d] * bf2f(y[s * 64 + lane]);
  atomicAdd(out + d * 64 + lane, v);
}

__global__ __launch_bounds__(256) void k_clip(float4* __restrict__ out, int n4) {
  int i = blockIdx.x * 256 + threadIdx.x;
  if (i >= n4) return;
  float4 v = out[i];
  v.x = fminf(fmaxf(v.x, -50.f), 50.f);
  v.y = fminf(fmaxf(v.y, -50.f), 50.f);
  v.z = fminf(fmaxf(v.z, -50.f), 50.f);
  v.w = fminf(fmaxf(v.w, -50.f), 50.f);
  out[i] = v;
}

// ---------------------------------------------------------------------------
extern "C" void kernel_launch(void* const* d_in, const int* in_sizes, int n_in,
                              void* d_out, int out_size, void* d_ws, size_t ws_size,
                              hipStream_t stream) {
  const float* h      = (const float*)d_in[1];
  const void*  ei_pos = d_in[2];
  const void*  ei_neg = d_in[3];
  const float* gamma  = (const float*)d_in[4];
  const float* beta   = (const float*)d_in[5];
  const float* W_pos  = (const float*)d_in[6];
  const float* b_pos  = (const float*)d_in[7];
  const float* W_neg  = (const float*)d_in[8];
  const float* b_neg  = (const float*)d_in[9];
  const float* Wp     = (const float*)d_in[10];
  const float* bp     = (const float*)d_in[11];
  const float* Wn     = (const float*)d_in[12];
  const float* bn     = (const float*)d_in[13];
  float* out = (float*)d_out;

  const int N = in_sizes[1] / HID;
  const int Ep = in_sizes[2] / 2;
  const int En = in_sizes[3] / 2;
  const int NBF = (N + RPB - 1) / RPB;
  const int nbins = 2 * NBF;
  const long long ET = (long long)Ep + En;

  float* ws = (float*)d_ws;
  size_t off = 0;
  auto alloc = [&](size_t nf) {
    float* p = ws + off;
    off = (off + nf + 63) & ~(size_t)63;
    return p;
  };
  // Common arrays.
  unsigned short* y_pos = (unsigned short*)alloc((size_t)N * HID / 2);
  unsigned short* y_neg = (unsigned short*)alloc((size_t)N * HID / 2);
  float* dinvp = alloc(N);
  float* dinvn = alloc(N);
  unsigned short* Mbt = (unsigned short*)alloc(128 * 64 / 2);
  float* cvec  = alloc(64);
  unsigned* flag = (unsigned*)alloc(64);
  // Fast-path arrays.
  unsigned* histG  = (unsigned*)alloc((size_t)nbins * NBB);
  unsigned* binTot = (unsigned*)alloc(MAXBINS);
  unsigned* offsB  = (unsigned*)alloc(nbins + 1);
  unsigned* offsp  = (unsigned*)alloc(N + 1);
  unsigned* offsn  = (unsigned*)alloc(N + 1);
  unsigned* binned = (unsigned*)alloc((size_t)ET);
  unsigned* csr    = (unsigned*)alloc((size_t)ET);
  const bool fast = (off * sizeof(float) <= ws_size) && (nbins <= MAXBINS) &&
                    (N < (1 << 20));

  k_prep<<<17, 256, 0, stream>>>(W_pos, W_neg, Wp, Wn, b_pos, b_neg, bp, bn,
                                 Mbt, cvec, (const unsigned*)ei_pos, flag, 2 * Ep);

  if (fast) {
    const long long chunk =
        ((ET + (long long)NBB * 256 - 1) / ((long long)NBB * 256)) * 256;
    k_hist<<<NBB, 256, 0, stream>>>(ei_pos, ei_neg, flag, histG, Ep, En, NBF, chunk);
    k_scanA<<<(nbins + 3) / 4, 256, 0, stream>>>(histG, binTot, nbins);
    k_scanB<<<1, 256, 0, stream>>>(binTot, offsB, nbins, ET);
    k_binscat<<<NBB, 256, 0, stream>>>(ei_pos, ei_neg, flag, histG, offsB, binned,
                                       Ep, En, NBF, chunk);
    k_binsort<<<NBF, 256, 0, stream>>>(binned, offsB, csr, offsp, offsn,
                                       dinvp, dinvn, N, NBF);
    k_ln_gemm<<<(N + 63) / 64, 256, 0, stream>>>(h, gamma, beta, Mbt, dinvp, dinvn,
                                                 y_pos, y_neg, N);
    const long long gthreads = (long long)N * 64;
    const int gblocks = (int)((gthreads + 255) / 256);
    k_gather1<0><<<gblocks, 256, 0, stream>>>(offsp, csr, dinvp, y_pos, cvec, out, N);
    k_gather1<1><<<gblocks, 256, 0, stream>>>(offsn, csr, dinvn, y_neg, cvec, out, N);
  } else {
    hipMemsetAsync(dinvp, 0, sizeof(float) * N, stream);
    hipMemsetAsync(dinvn, 0, sizeof(float) * N, stream);
    k_deg<<<(Ep + 255) / 256, 256, 0, stream>>>(ei_pos, flag, dinvp, Ep);
    k_deg<<<(En + 255) / 256, 256, 0, stream>>>(ei_neg, flag, dinvn, En);
    k_dinv<<<(N + 255) / 256, 256, 0, stream>>>(dinvp, dinvn, N);
    k_ln_gemm<<<(N + 63) / 64, 256, 0, stream>>>(h, gamma, beta, Mbt, dinvp, dinvn,
                                                 y_pos, y_neg, N);
    const long long n = (long long)N * 64;
    k_init_out<<<(int)((n + 255) / 256), 256, 0, stream>>>(y_pos, y_neg, dinvp, dinvn,
                                                           cvec, out, n);
    const long long st = (long long)Ep * 64;
    k_scatter<<<(int)((st + 255) / 256), 256, 0, stream>>>(ei_pos, flag, dinvp, y_pos,
                                                           out, Ep);
    const long long stn = (long long)En * 64;
    k_scatter<<<(int)((stn + 255) / 256), 256, 0, stream>>>(ei_neg, flag, dinvn, y_neg,
                                                            out, En);
    const int n4 = N * 16;
    k_clip<<<(n4 + 255) / 256, 256, 0, stream>>>((float4*)out, n4);
  }
}

// Round 12
// 146.558 us; speedup vs baseline: 1.1437x; 1.1437x over previous
//
#include <hip/hip_runtime.h>
#include <stdint.h>

#define HID 64
#define RPB 128          // rows per dst bin
#define NBB 512          // blocks for hist/binscat streaming passes
#define TBS 1024         // threads per block for hist/binscat (occupancy)
#define MAXBINS 2048     // need 2*NBF <= MAXBINS

typedef __attribute__((ext_vector_type(8))) short bf16x8;
typedef __attribute__((ext_vector_type(4))) float f32x4;

// ---------------------------------------------------------------------------
// bf16 helpers (RTNE pack, cheap unpack).
__device__ inline float bf2f(unsigned short u) {
  return __uint_as_float(((unsigned)u) << 16);
}
__device__ inline unsigned short f2bf(float f) {
  unsigned u = __float_as_uint(f);
  unsigned r = u + 0x7FFFu + ((u >> 16) & 1u);
  return (unsigned short)(r >> 16);
}
__device__ inline unsigned pk2(float a, float b) {
  return (unsigned)f2bf(a) | ((unsigned)f2bf(b) << 16);
}

// ---------------------------------------------------------------------------
// Mbt = bf16, transposed fused weights; cvec = fused bias. Block 16 detects
// edge dtype (int64 vs int32) from high words of the first 1024 values.
__global__ __launch_bounds__(256) void k_prep(
    const float* __restrict__ Wpos, const float* __restrict__ Wneg,
    const float* __restrict__ Wp, const float* __restrict__ Wn,
    const float* __restrict__ bpos, const float* __restrict__ bneg,
    const float* __restrict__ bp, const float* __restrict__ bn,
    unsigned short* __restrict__ Mbt, float* __restrict__ cvec,
    const unsigned* __restrict__ eiw, unsigned* __restrict__ flag, int nWords) {
  if (blockIdx.x == 16) {
    __shared__ unsigned acc;
    if (threadIdx.x == 0) acc = 0u;
    __syncthreads();
    unsigned bad = 0u;
    for (int i = 0; i < 4; ++i) {
      int w = (i * 256 + (int)threadIdx.x) * 2 + 1;
      if (w < nWords) bad |= eiw[w];
    }
    if (bad) atomicOr(&acc, 1u);
    __syncthreads();
    if (threadIdx.x == 0) *flag = (acc == 0u) ? 1u : 0u;  // 1 => int64
    return;
  }
  int idx = blockIdx.x * 256 + threadIdx.x;
  int i = idx >> 6, j = idx & 63;   // i = k (LN dim), j = output col
  float a = 0.f, b = 0.f;
  for (int k = 0; k < 64; ++k) {
    a += Wpos[i * 64 + k] * Wp[k * 64 + j];
    b += Wneg[i * 64 + k] * Wn[k * 64 + j];
  }
  Mbt[j * 64 + i] = f2bf(a);
  Mbt[(64 + j) * 64 + i] = f2bf(b);
  if (blockIdx.x == 0 && threadIdx.x < 64) {
    int jj = threadIdx.x;
    float acc = bp[jj] + bn[jj];
    for (int k = 0; k < 64; ++k)
      acc += bpos[k] * Wp[k * 64 + jj] + bneg[k] * Wn[k * 64 + jj];
    cvec[jj] = acc;
  }
}

// ---------------------------------------------------------------------------
// Pass 1: per-block LDS histogram of dst bins. histG layout: [bin][block].
// 1024 threads/block: 512 blocks x 16 waves = full occupancy (round-11 fix:
// this pass was latency-bound at 15% occupancy with 256 threads).
__global__ __launch_bounds__(TBS) void k_hist(
    const void* __restrict__ eip, const void* __restrict__ ein,
    const unsigned* __restrict__ flag, unsigned* __restrict__ histG,
    int Ep, int En, int NBF, long long chunk) {
  __shared__ unsigned hist[MAXBINS];
  const int nbins = 2 * NBF;
  for (int i = threadIdx.x; i < nbins; i += TBS) hist[i] = 0u;
  __syncthreads();
  const long long ET = (long long)Ep + En;
  long long beg = (long long)blockIdx.x * chunk;
  long long end = beg + chunk;
  if (end > ET) end = ET;
  const bool is64 = (*flag != 0u);
  for (long long e = beg + threadIdx.x; e < end; e += TBS) {
    int seg = e >= Ep;
    long long ee = seg ? e - Ep : e;
    const void* ei = seg ? ein : eip;
    long long Ecur = seg ? En : Ep;
    int d;
    if (is64) d = (int)((const long long*)ei)[Ecur + ee];
    else      d = ((const int*)ei)[Ecur + ee];
    atomicAdd(&hist[seg * NBF + (d >> 7)], 1u);
  }
  __syncthreads();
  for (int i = threadIdx.x; i < nbins; i += TBS)
    histG[(size_t)i * NBB + blockIdx.x] = hist[i];
}

// ---------------------------------------------------------------------------
// Pass 2a: one wave per bin — exclusive prefix across blocks, emit totals.
__global__ __launch_bounds__(256) void k_scanA(unsigned* __restrict__ histG,
                                               unsigned* __restrict__ binTot,
                                               int nbins) {
  const int w = threadIdx.x >> 6, lane = threadIdx.x & 63;
  const int b = blockIdx.x * 4 + w;
  if (b >= nbins) return;
  unsigned* row = histG + (size_t)b * NBB;
  unsigned carry = 0u;
  for (int c = 0; c < NBB; c += 64) {
    unsigned v = row[c + lane];
    unsigned incl = v;
#pragma unroll
    for (int o = 1; o < 64; o <<= 1) {
      unsigned x = __shfl_up(incl, o);
      if (lane >= o) incl += x;
    }
    row[c + lane] = incl - v + carry;
    carry += __shfl(incl, 63);
  }
  if (lane == 0) binTot[b] = carry;
}

// Pass 2b: single block — exclusive scan of bin totals -> offsB.
__global__ __launch_bounds__(256) void k_scanB(const unsigned* __restrict__ binTot,
                                               unsigned* __restrict__ offsB,
                                               int nbins, long long ET) {
  __shared__ unsigned sh[MAXBINS];
  const int t = threadIdx.x;
  for (int i = t; i < MAXBINS; i += 256) sh[i] = (i < nbins) ? binTot[i] : 0u;
  __syncthreads();
  for (int off = 1; off < MAXBINS; off <<= 1) {
    unsigned v[MAXBINS / 256];
#pragma unroll
    for (int k = 0; k < MAXBINS / 256; ++k) {
      int i = t + k * 256;
      v[k] = (i >= off) ? sh[i - off] : 0u;
    }
    __syncthreads();
#pragma unroll
    for (int k = 0; k < MAXBINS / 256; ++k) sh[t + k * 256] += v[k];
    __syncthreads();
  }
  for (int i = t; i < nbins; i += 256) offsB[i] = (i == 0) ? 0u : sh[i - 1];
  if (t == 0) offsB[nbins] = (unsigned)ET;
}

// ---------------------------------------------------------------------------
// Pass 3: scatter packed records src|(dlocal<<20) into per-(block,bin)
// sequential runs. 1024 threads/block (same NBB -> same run lengths, 4x the
// latency hiding).
__global__ __launch_bounds__(TBS) void k_binscat(
    const void* __restrict__ eip, const void* __restrict__ ein,
    const unsigned* __restrict__ flag, const unsigned* __restrict__ histG,
    const unsigned* __restrict__ offsB, unsigned* __restrict__ binned,
    int Ep, int En, int NBF, long long chunk) {
  __shared__ unsigned cur[MAXBINS];
  const int nbins = 2 * NBF;
  for (int i = threadIdx.x; i < nbins; i += TBS)
    cur[i] = histG[(size_t)i * NBB + blockIdx.x] + offsB[i];
  __syncthreads();
  const long long ET = (long long)Ep + En;
  long long beg = (long long)blockIdx.x * chunk;
  long long end = beg + chunk;
  if (end > ET) end = ET;
  const bool is64 = (*flag != 0u);
  for (long long e = beg + threadIdx.x; e < end; e += TBS) {
    int seg = e >= Ep;
    long long ee = seg ? e - Ep : e;
    const void* ei = seg ? ein : eip;
    long long Ecur = seg ? En : Ep;
    int s, d;
    if (is64) {
      const long long* p = (const long long*)ei;
      s = (int)p[ee]; d = (int)p[Ecur + ee];
    } else {
      const int* p = (const int*)ei;
      s = p[ee]; d = p[Ecur + ee];
    }
    unsigned pos = atomicAdd(&cur[seg * NBF + (d >> 7)], 1u);
    binned[pos] = (unsigned)s | ((unsigned)(d & 127) << 20);
  }
}

// ---------------------------------------------------------------------------
// Pass 4: one block per bin — counting-sort by dlocal -> per-node CSR,
// offs + dinv. 512 threads (was 256; occupancy).
__global__ __launch_bounds__(512) void k_binsort(
    const unsigned* __restrict__ binned, const unsigned* __restrict__ offsB,
    unsigned* __restrict__ csr, unsigned* __restrict__ offsp,
    unsigned* __restrict__ offsn, float* __restrict__ dinvp,
    float* __restrict__ dinvn, int N, int NBF) {
  __shared__ unsigned cnt[RPB], sc[RPB], cur[RPB];
  const int t = threadIdx.x;
  const int b = blockIdx.x;
  for (int seg = 0; seg < 2; ++seg) {
    const unsigned sb = offsB[seg * NBF + b];
    const unsigned se = offsB[seg * NBF + b + 1];
    if (t < RPB) cnt[t] = 0u;
    __syncthreads();
    for (unsigned i = sb + t; i < se; i += 512)
      atomicAdd(&cnt[binned[i] >> 20], 1u);
    __syncthreads();
    if (t < RPB) sc[t] = cnt[t];
    __syncthreads();
#pragma unroll
    for (int o = 1; o < RPB; o <<= 1) {
      unsigned v = 0u;
      if (t < RPB && t >= o) v = sc[t - o];
      __syncthreads();
      if (t < RPB) sc[t] += v;
      __syncthreads();
    }
    if (t < RPB) {
      unsigned excl = sc[t] - cnt[t];
      cur[t] = sb + excl;
      int g = b * RPB + t;
      if (g < N) {
        if (seg == 0) {
          offsp[g] = sb + excl;
          dinvp[g] = rsqrtf((float)cnt[t] + 1.0f);
        } else {
          offsn[g] = sb + excl;
          dinvn[g] = rsqrtf((float)cnt[t] + 1.0f);
        }
      }
    }
    __syncthreads();
    for (unsigned i = sb + t; i < se; i += 512) {
      unsigned w = binned[i];
      unsigned p = atomicAdd(&cur[w >> 20], 1u);
      csr[p] = w & 0xFFFFFu;
    }
    __syncthreads();
  }
  if (b == 0 && t == 0) {
    offsp[N] = offsB[NBF];
    offsn[N] = offsB[2 * NBF];
  }
}

// ---------------------------------------------------------------------------
// Fused LayerNorm + dual GEMM via MFMA (bf16 in, fp32 acc), epilogue scales by
// dinv[row], stores bf16. Block = 256 threads = 4 waves, 64 rows.
__global__ __launch_bounds__(256) void k_ln_gemm(
    const float* __restrict__ h, const float* __restrict__ gamma,
    const float* __restrict__ beta, const unsigned short* __restrict__ Mbt,
    const float* __restrict__ dinvp, const float* __restrict__ dinvn,
    unsigned short* __restrict__ yp, unsigned short* __restrict__ yn, int N) {
  __shared__ __align__(16) unsigned short Abf[64][72];
  __shared__ __align__(16) unsigned short Bt[128][72];
  const int t = threadIdx.x;
  const int r0 = blockIdx.x * 64;

  // Stage B: 128 rows x 64 bf16 = 1024 uint4; 4 uint4 per thread.
#pragma unroll
  for (int i = 0; i < 4; ++i) {
    int f = i * 256 + t;
    int n = f >> 3, c8 = f & 7;
    *(uint4*)(&Bt[n][c8 * 8]) = ((const uint4*)Mbt)[f];
  }

  // LayerNorm: thread (r = t>>2, p = t&3) handles 16 cols of row r0+r.
  const int r = t >> 2, p = t & 3;
  float4 va, vb, vc, vd;
  if (r0 + r < N) {
    const float4* hp = (const float4*)(h + (size_t)(r0 + r) * 64 + p * 16);
    va = hp[0]; vb = hp[1]; vc = hp[2]; vd = hp[3];
  } else {
    va = vb = vc = vd = make_float4(0.f, 0.f, 0.f, 0.f);
  }
  float s  = (va.x + va.y + va.z + va.w) + (vb.x + vb.y + vb.z + vb.w) +
             (vc.x + vc.y + vc.z + vc.w) + (vd.x + vd.y + vd.z + vd.w);
  float ss = (va.x*va.x + va.y*va.y + va.z*va.z + va.w*va.w) +
             (vb.x*vb.x + vb.y*vb.y + vb.z*vb.z + vb.w*vb.w) +
             (vc.x*vc.x + vc.y*vc.y + vc.z*vc.z + vc.w*vc.w) +
             (vd.x*vd.x + vd.y*vd.y + vd.z*vd.z + vd.w*vd.w);
  s  += __shfl_xor(s, 1);  ss += __shfl_xor(ss, 1);
  s  += __shfl_xor(s, 2);  ss += __shfl_xor(ss, 2);
  float mu = s * (1.f / 64.f);
  float var = ss * (1.f / 64.f) - mu * mu;
  float rstd = rsqrtf(var + 1e-5f);
  {
    const float4* g4 = (const float4*)(gamma + p * 16);
    const float4* b4 = (const float4*)(beta + p * 16);
    float4 g0 = g4[0], g1 = g4[1], g2 = g4[2], g3 = g4[3];
    float4 e0 = b4[0], e1 = b4[1], e2 = b4[2], e3 = b4[3];
#define LNV(v, g, e) ((v - mu) * rstd * g + e)
    unsigned w0 = pk2(LNV(va.x, g0.x, e0.x), LNV(va.y, g0.y, e0.y));
    unsigned w1 = pk2(LNV(va.z, g0.z, e0.z), LNV(va.w, g0.w, e0.w));
    unsigned w2 = pk2(LNV(vb.x, g1.x, e1.x), LNV(vb.y, g1.y, e1.y));
    unsigned w3 = pk2(LNV(vb.z, g1.z, e1.z), LNV(vb.w, g1.w, e1.w));
    unsigned w4 = pk2(LNV(vc.x, g2.x, e2.x), LNV(vc.y, g2.y, e2.y));
    unsigned w5 = pk2(LNV(vc.z, g2.z, e2.z), LNV(vc.w, g2.w, e2.w));
    unsigned w6 = pk2(LNV(vd.x, g3.x, e3.x), LNV(vd.y, g3.y, e3.y));
    unsigned w7 = pk2(LNV(vd.z, g3.z, e3.z), LNV(vd.w, g3.w, e3.w));
#undef LNV
    *(uint4*)(&Abf[r][p * 16]) = make_uint4(w0, w1, w2, w3);
    *(uint4*)(&Abf[r][p * 16 + 8]) = make_uint4(w4, w5, w6, w7);
  }
  __syncthreads();

  // MFMA phase.
  const int w = t >> 6, lane = t & 63;
  const int mrow = lane & 15, grp = lane >> 4;
  bf16x8 a0 = *(const bf16x8*)(&Abf[w * 16 + mrow][grp * 8]);
  bf16x8 a1 = *(const bf16x8*)(&Abf[w * 16 + mrow][32 + grp * 8]);
  float sp[4], sn[4];
#pragma unroll
  for (int reg = 0; reg < 4; ++reg) {
    int grow = r0 + w * 16 + grp * 4 + reg;
    sp[reg] = (grow < N) ? dinvp[grow] : 0.f;
    sn[reg] = (grow < N) ? dinvn[grow] : 0.f;
  }
#pragma unroll
  for (int ct = 0; ct < 8; ++ct) {
    const int n = ct * 16 + mrow;
    bf16x8 b0 = *(const bf16x8*)(&Bt[n][grp * 8]);
    bf16x8 b1 = *(const bf16x8*)(&Bt[n][32 + grp * 8]);
    f32x4 acc = {0.f, 0.f, 0.f, 0.f};
    acc = __builtin_amdgcn_mfma_f32_16x16x32_bf16(a0, b0, acc, 0, 0, 0);
    acc = __builtin_amdgcn_mfma_f32_16x16x32_bf16(a1, b1, acc, 0, 0, 0);
#pragma unroll
    for (int reg = 0; reg < 4; ++reg) {
      int grow = r0 + w * 16 + grp * 4 + reg;
      if (grow < N) {
        if (ct < 4)
          yp[(size_t)grow * 64 + ct * 16 + mrow] = f2bf(sp[reg] * acc[reg]);
        else
          yn[(size_t)grow * 64 + (ct - 4) * 16 + mrow] = f2bf(sn[reg] * acc[reg]);
      }
    }
  }
}

// ---------------------------------------------------------------------------
// Gather (round-9 proven form): one wave per dst node, FOUR 16-lane groups,
// uint2/lane, 2-deep unroll -> 8 rows in flight. All __shfl execute
// wave-uniformly with clamped source index (ds_bpermute from EXEC-inactive
// source lane is undefined); only loads/accumulates are predicated.
__global__ __launch_bounds__(256) void k_gather(
    const unsigned* __restrict__ offsp, const unsigned* __restrict__ offsn,
    const unsigned* __restrict__ csr, const float* __restrict__ dinvp,
    const float* __restrict__ dinvn, const unsigned short* __restrict__ yp,
    const unsigned short* __restrict__ yn, const float* __restrict__ cvec,
    float* __restrict__ out, int N) {
  const int lane = threadIdx.x & 63;
  const int grp = lane >> 4;     // 0..3
  const int lc = lane & 15;      // column group: cols lc*4..lc*4+3
  const int d = (int)(((long long)blockIdx.x * 256 + threadIdx.x) >> 6);
  if (d >= N) return;

  float4 ap = make_float4(0.f, 0.f, 0.f, 0.f);
  float4 an = make_float4(0.f, 0.f, 0.f, 0.f);

#define ACC4(ACC, U)                                                         \
  ACC.x += bf2f((unsigned short)(U.x & 0xFFFFu));                            \
  ACC.y += bf2f((unsigned short)(U.x >> 16));                                \
  ACC.z += bf2f((unsigned short)(U.y & 0xFFFFu));                            \
  ACC.w += bf2f((unsigned short)(U.y >> 16));

#define GATHER_SEG(OFFS, Y, ACC)                                             \
  {                                                                          \
    unsigned beg = OFFS[d], end = OFFS[d + 1];                               \
    for (unsigned base = beg; base < end; base += 64u) {                     \
      int m = (int)min(64u, end - base);                                     \
      int idx = (base + (unsigned)lane < end) ? (int)csr[base + lane] : 0;   \
      int j = 0;                                                             \
      for (; j + 7 < m; j += 8) {                                            \
        int s0 = __shfl(idx, j + grp);                                       \
        int s1 = __shfl(idx, j + 4 + grp);                                   \
        uint2 u0 = *(const uint2*)(Y + (size_t)s0 * 64 + 4 * lc);            \
        uint2 u1 = *(const uint2*)(Y + (size_t)s1 * 64 + 4 * lc);            \
        ACC4(ACC, u0)                                                        \
        ACC4(ACC, u1)                                                        \
      }                                                                      \
      for (; j < m; j += 4) {                                                \
        int e = j + grp;                                                     \
        int es = (e < m) ? e : (m - 1);  /* clamp: source lane stays valid */\
        int s0 = __shfl(idx, es);        /* executed by ALL lanes */         \
        if (e < m) {                                                         \
          uint2 u0 = *(const uint2*)(Y + (size_t)s0 * 64 + 4 * lc);          \
          ACC4(ACC, u0)                                                      \
        }                                                                    \
      }                                                                      \
    }                                                                        \
  }

  GATHER_SEG(offsp, yp, ap)
  GATHER_SEG(offsn, yn, an)
#undef GATHER_SEG

  // Combine the 4 groups (butterfly over fully-active wave).
  ap.x += __shfl_xor(ap.x, 16); ap.y += __shfl_xor(ap.y, 16);
  ap.z += __shfl_xor(ap.z, 16); ap.w += __shfl_xor(ap.w, 16);
  an.x += __shfl_xor(an.x, 16); an.y += __shfl_xor(an.y, 16);
  an.z += __shfl_xor(an.z, 16); an.w += __shfl_xor(an.w, 16);
  ap.x += __shfl_xor(ap.x, 32); ap.y += __shfl_xor(ap.y, 32);
  ap.z += __shfl_xor(ap.z, 32); ap.w += __shfl_xor(ap.w, 32);
  an.x += __shfl_xor(an.x, 32); an.y += __shfl_xor(an.y, 32);
  an.z += __shfl_xor(an.z, 32); an.w += __shfl_xor(an.w, 32);

  if (lane < 16) {
    // Self-loop rows (counted once).
    uint2 up = *(const uint2*)(yp + (size_t)d * 64 + 4 * lc);
    uint2 un = *(const uint2*)(yn + (size_t)d * 64 + 4 * lc);
    ap.x += bf2f((unsigned short)(up.x & 0xFFFFu));
    ap.y += bf2f((unsigned short)(up.x >> 16));
    ap.z += bf2f((unsigned short)(up.y & 0xFFFFu));
    ap.w += bf2f((unsigned short)(up.y >> 16));
    an.x += bf2f((unsigned short)(un.x & 0xFFFFu));
    an.y += bf2f((unsigned short)(un.x >> 16));
    an.z += bf2f((unsigned short)(un.y & 0xFFFFu));
    an.w += bf2f((unsigned short)(un.y >> 16));
    float dp = dinvp[d], dn = dinvn[d];
    float4 cc = *(const float4*)(cvec + 4 * lc);
    float4 v;
    v.x = fminf(fmaxf(cc.x + dp * ap.x + dn * an.x, -50.f), 50.f);
    v.y = fminf(fmaxf(cc.y + dp * ap.y + dn * an.y, -50.f), 50.f);
    v.z = fminf(fmaxf(cc.z + dp * ap.z + dn * an.z, -50.f), 50.f);
    v.w = fminf(fmaxf(cc.w + dp * ap.w + dn * an.w, -50.f), 50.f);
    *(float4*)(out + (size_t)d * 64 + 4 * lc) = v;
  }
#undef ACC4
}

// ---------------------------------------------------------------------------
// Fallback path (atomic scatter), bf16 y pre-scaled by dinv[src].
__global__ __launch_bounds__(256) void k_deg(const void* __restrict__ ei,
                                             const unsigned* __restrict__ flag,
                                             float* __restrict__ deg, int E) {
  int e = blockIdx.x * 256 + threadIdx.x;
  if (e >= E) return;
  long long d;
  if (*flag) d = ((const long long*)ei)[(long long)E + e];
  else       d = (long long)((const int*)ei)[(long long)E + e];
  atomicAdd(&deg[(int)d], 1.0f);
}

__global__ __launch_bounds__(256) void k_dinv(float* __restrict__ degp,
                                              float* __restrict__ degn, int N) {
  int i = blockIdx.x * 256 + threadIdx.x;
  if (i < N) {
    degp[i] = rsqrtf(degp[i] + 1.0f);
    degn[i] = rsqrtf(degn[i] + 1.0f);
  }
}

__global__ __launch_bounds__(256) void k_init_out(
    const unsigned short* __restrict__ yp, const unsigned short* __restrict__ yn,
    const float* __restrict__ dinvp, const float* __restrict__ dinvn,
    const float* __restrict__ cvec, float* __restrict__ out, long long n) {
  long long i = (long long)blockIdx.x * 256 + threadIdx.x;
  if (i >= n) return;
  int row = (int)(i >> 6), col = (int)(i & 63);
  out[i] = cvec[col] + dinvp[row] * bf2f(yp[i]) + dinvn[row] * bf2f(yn[i]);
}

__global__ __launch_bounds__(256) void k_scatter(
    const void* __restrict__ ei, const unsigned* __restrict__ flag,
    const float* __restrict__ dinv, const unsigned short* __restrict__ y,
    float* __restrict__ out, int E) {
  const int lane = threadIdx.x & 63;
  long long e = ((long long)blockIdx.x * 256 + threadIdx.x) >> 6;
  if (e >= E) return;
  long long s, d;
  if (*flag) {
    const long long* p = (const long long*)ei;
    s = p[e]; d = p[E + e];
  } else {
    const int* p = (const int*)ei;
    s = (long long)p[e]; d = (long long)p[E + e];
  }
  float v = dinv[(int)d] * bf2f(y[s * 64 + lane]);
  atomicAdd(out + d * 64 + lane, v);
}

__global__ __launch_bounds__(256) void k_clip(float4* __restrict__ out, int n4) {
  int i = blockIdx.x * 256 + threadIdx.x;
  if (i >= n4) return;
  float4 v = out[i];
  v.x = fminf(fmaxf(v.x, -50.f), 50.f);
  v.y = fminf(fmaxf(v.y, -50.f), 50.f);
  v.z = fminf(fmaxf(v.z, -50.f), 50.f);
  v.w = fminf(fmaxf(v.w, -50.f), 50.f);
  out[i] = v;
}

// ---------------------------------------------------------------------------
extern "C" void kernel_launch(void* const* d_in, const int* in_sizes, int n_in,
                              void* d_out, int out_size, void* d_ws, size_t ws_size,
                              hipStream_t stream) {
  const float* h      = (const float*)d_in[1];
  const void*  ei_pos = d_in[2];
  const void*  ei_neg = d_in[3];
  const float* gamma  = (const float*)d_in[4];
  const float* beta   = (const float*)d_in[5];
  const float* W_pos  = (const float*)d_in[6];
  const float* b_pos  = (const float*)d_in[7];
  const float* W_neg  = (const float*)d_in[8];
  const float* b_neg  = (const float*)d_in[9];
  const float* Wp     = (const float*)d_in[10];
  const float* bp     = (const float*)d_in[11];
  const float* Wn     = (const float*)d_in[12];
  const float* bn     = (const float*)d_in[13];
  float* out = (float*)d_out;

  const int N = in_sizes[1] / HID;
  const int Ep = in_sizes[2] / 2;
  const int En = in_sizes[3] / 2;
  const int NBF = (N + RPB - 1) / RPB;
  const int nbins = 2 * NBF;
  const long long ET = (long long)Ep + En;

  float* ws = (float*)d_ws;
  size_t off = 0;
  auto alloc = [&](size_t nf) {
    float* p = ws + off;
    off = (off + nf + 63) & ~(size_t)63;
    return p;
  };
  // Common arrays.
  unsigned short* y_pos = (unsigned short*)alloc((size_t)N * HID / 2);
  unsigned short* y_neg = (unsigned short*)alloc((size_t)N * HID / 2);
  float* dinvp = alloc(N);
  float* dinvn = alloc(N);
  unsigned short* Mbt = (unsigned short*)alloc(128 * 64 / 2);
  float* cvec  = alloc(64);
  unsigned* flag = (unsigned*)alloc(64);
  // Fast-path arrays.
  unsigned* histG  = (unsigned*)alloc((size_t)nbins * NBB);
  unsigned* binTot = (unsigned*)alloc(MAXBINS);
  unsigned* offsB  = (unsigned*)alloc(nbins + 1);
  unsigned* offsp  = (unsigned*)alloc(N + 1);
  unsigned* offsn  = (unsigned*)alloc(N + 1);
  unsigned* binned = (unsigned*)alloc((size_t)ET);
  unsigned* csr    = (unsigned*)alloc((size_t)ET);
  const bool fast = (off * sizeof(float) <= ws_size) && (nbins <= MAXBINS) &&
                    (N < (1 << 20));

  k_prep<<<17, 256, 0, stream>>>(W_pos, W_neg, Wp, Wn, b_pos, b_neg, bp, bn,
                                 Mbt, cvec, (const unsigned*)ei_pos, flag, 2 * Ep);

  if (fast) {
    // chunk: multiple of TBS so per-block stride loops stay aligned.
    const long long chunk =
        ((ET + (long long)NBB * TBS - 1) / ((long long)NBB * TBS)) * TBS;
    k_hist<<<NBB, TBS, 0, stream>>>(ei_pos, ei_neg, flag, histG, Ep, En, NBF, chunk);
    k_scanA<<<(nbins + 3) / 4, 256, 0, stream>>>(histG, binTot, nbins);
    k_scanB<<<1, 256, 0, stream>>>(binTot, offsB, nbins, ET);
    k_binscat<<<NBB, TBS, 0, stream>>>(ei_pos, ei_neg, flag, histG, offsB, binned,
                                       Ep, En, NBF, chunk);
    k_binsort<<<NBF, 512, 0, stream>>>(binned, offsB, csr, offsp, offsn,
                                       dinvp, dinvn, N, NBF);
    k_ln_gemm<<<(N + 63) / 64, 256, 0, stream>>>(h, gamma, beta, Mbt, dinvp, dinvn,
                                                 y_pos, y_neg, N);
    const long long gthreads = (long long)N * 64;
    k_gather<<<(int)((gthreads + 255) / 256), 256, 0, stream>>>(
        offsp, offsn, csr, dinvp, dinvn, y_pos, y_neg, cvec, out, N);
  } else {
    hipMemsetAsync(dinvp, 0, sizeof(float) * N, stream);
    hipMemsetAsync(dinvn, 0, sizeof(float) * N, stream);
    k_deg<<<(Ep + 255) / 256, 256, 0, stream>>>(ei_pos, flag, dinvp, Ep);
    k_deg<<<(En + 255) / 256, 256, 0, stream>>>(ei_neg, flag, dinvn, En);
    k_dinv<<<(N + 255) / 256, 256, 0, stream>>>(dinvp, dinvn, N);
    k_ln_gemm<<<(N + 63) / 64, 256, 0, stream>>>(h, gamma, beta, Mbt, dinvp, dinvn,
                                                 y_pos, y_neg, N);
    const long long n = (long long)N * 64;
    k_init_out<<<(int)((n + 255) / 256), 256, 0, stream>>>(y_pos, y_neg, dinvp, dinvn,
                                                           cvec, out, n);
    const long long st = (long long)Ep * 64;
    k_scatter<<<(int)((st + 255) / 256), 256, 0, stream>>>(ei_pos, flag, dinvp, y_pos,
                                                           out, Ep);
    const long long stn = (long long)En * 64;
    k_scatter<<<(int)((stn + 255) / 256), 256, 0, stream>>>(ei_neg, flag, dinvn, y_neg,
                                                            out, En);
    const int n4 = N * 16;
    k_clip<<<(n4 + 255) / 256, 256, 0, stream>>>((float4*)out, n4);
  }
}

// Round 13
// 146.492 us; speedup vs baseline: 1.1442x; 1.0005x over previous
//
#include <hip/hip_runtime.h>
#include <stdint.h>

#define HID 64
#define RPB 128          // rows per dst bin
#define NBB 512          // blocks for hist/binscat streaming passes
#define TBS 1024         // threads per block for hist/binscat (occupancy)
#define MAXBINS 2048     // need 2*NBF <= MAXBINS

typedef __attribute__((ext_vector_type(8))) short bf16x8;
typedef __attribute__((ext_vector_type(4))) float f32x4;

// ---------------------------------------------------------------------------
// bf16 helpers (RTNE pack, cheap unpack).
__device__ inline float bf2f(unsigned short u) {
  return __uint_as_float(((unsigned)u) << 16);
}
__device__ inline unsigned short f2bf(float f) {
  unsigned u = __float_as_uint(f);
  unsigned r = u + 0x7FFFu + ((u >> 16) & 1u);
  return (unsigned short)(r >> 16);
}
__device__ inline unsigned pk2(float a, float b) {
  return (unsigned)f2bf(a) | ((unsigned)f2bf(b) << 16);
}

// ---------------------------------------------------------------------------
// Fallback-path prep (with detect block). Fast path uses k_hist_prep below.
__global__ __launch_bounds__(256) void k_prep(
    const float* __restrict__ Wpos, const float* __restrict__ Wneg,
    const float* __restrict__ Wp, const float* __restrict__ Wn,
    const float* __restrict__ bpos, const float* __restrict__ bneg,
    const float* __restrict__ bp, const float* __restrict__ bn,
    unsigned short* __restrict__ Mbt, float* __restrict__ cvec,
    const unsigned* __restrict__ eiw, unsigned* __restrict__ flag, int nWords) {
  if (blockIdx.x == 16) {
    __shared__ unsigned acc;
    if (threadIdx.x == 0) acc = 0u;
    __syncthreads();
    unsigned bad = 0u;
    for (int i = 0; i < 4; ++i) {
      int w = (i * 256 + (int)threadIdx.x) * 2 + 1;
      if (w < nWords) bad |= eiw[w];
    }
    if (bad) atomicOr(&acc, 1u);
    __syncthreads();
    if (threadIdx.x == 0) *flag = (acc == 0u) ? 1u : 0u;  // 1 => int64
    return;
  }
  int idx = blockIdx.x * 256 + threadIdx.x;
  int i = idx >> 6, j = idx & 63;
  float a = 0.f, b = 0.f;
  for (int k = 0; k < 64; ++k) {
    a += Wpos[i * 64 + k] * Wp[k * 64 + j];
    b += Wneg[i * 64 + k] * Wn[k * 64 + j];
  }
  Mbt[j * 64 + i] = f2bf(a);
  Mbt[(64 + j) * 64 + i] = f2bf(b);
  if (blockIdx.x == 0 && threadIdx.x < 64) {
    int jj = threadIdx.x;
    float acc = bp[jj] + bn[jj];
    for (int k = 0; k < 64; ++k)
      acc += bpos[k] * Wp[k * 64 + jj] + bneg[k] * Wn[k * 64 + jj];
    cvec[jj] = acc;
  }
}

// ---------------------------------------------------------------------------
// Per-block edge-dtype detect (int64 => all high words of first 1024 values
// are 0; int32 random values make that probability ~0). 4 KB read, L2-hot.
__device__ inline bool detect_is64(const unsigned* __restrict__ eiw, int nWords,
                                   unsigned* shflag, int tid, int nthreads) {
  if (tid == 0) *shflag = 0u;
  __syncthreads();
  if (tid < 1024) {
    int w = 2 * tid + 1;
    unsigned v = (w < nWords) ? eiw[w] : 0u;
    if (v) atomicOr(shflag, 1u);
  }
  __syncthreads();
  return (*shflag == 0u);
}

// ---------------------------------------------------------------------------
// Pass 1 (fused): blocks < NBB build the per-block LDS histogram of dst bins
// (histG layout [bin][block]); blocks >= NBB compute Mbt/cvec (weight fusion).
__global__ __launch_bounds__(TBS) void k_hist_prep(
    const void* __restrict__ eip, const void* __restrict__ ein,
    unsigned* __restrict__ histG, int Ep, int En, int NBF, long long chunk,
    const float* __restrict__ Wpos, const float* __restrict__ Wneg,
    const float* __restrict__ Wp, const float* __restrict__ Wn,
    const float* __restrict__ bpos, const float* __restrict__ bneg,
    const float* __restrict__ bp, const float* __restrict__ bn,
    unsigned short* __restrict__ Mbt, float* __restrict__ cvec) {
  const int t = threadIdx.x;
  if (blockIdx.x >= NBB) {
    // Prep blocks: 4096 output elements over 4 blocks of 1024 threads.
    int idx = (int)(blockIdx.x - NBB) * TBS + t;
    if (idx < 4096) {
      int i = idx >> 6, j = idx & 63;
      float a = 0.f, b = 0.f;
      for (int k = 0; k < 64; ++k) {
        a += Wpos[i * 64 + k] * Wp[k * 64 + j];
        b += Wneg[i * 64 + k] * Wn[k * 64 + j];
      }
      Mbt[j * 64 + i] = f2bf(a);
      Mbt[(64 + j) * 64 + i] = f2bf(b);
    }
    if (blockIdx.x == NBB && t < 64) {
      float acc = bp[t] + bn[t];
      for (int k = 0; k < 64; ++k)
        acc += bpos[k] * Wp[k * 64 + t] + bneg[k] * Wn[k * 64 + t];
      cvec[t] = acc;
    }
    return;
  }
  __shared__ unsigned hist[MAXBINS];
  __shared__ unsigned shflag;
  const int nbins = 2 * NBF;
  for (int i = t; i < nbins; i += TBS) hist[i] = 0u;
  const bool is64 = detect_is64((const unsigned*)eip, 2 * Ep, &shflag, t, TBS);
  const long long ET = (long long)Ep + En;
  long long beg = (long long)blockIdx.x * chunk;
  long long end = beg + chunk;
  if (end > ET) end = ET;
  for (long long e = beg + t; e < end; e += TBS) {
    int seg = e >= Ep;
    long long ee = seg ? e - Ep : e;
    const void* ei = seg ? ein : eip;
    long long Ecur = seg ? En : Ep;
    int d;
    if (is64) d = (int)((const long long*)ei)[Ecur + ee];
    else      d = ((const int*)ei)[Ecur + ee];
    atomicAdd(&hist[seg * NBF + (d >> 7)], 1u);
  }
  __syncthreads();
  for (int i = t; i < nbins; i += TBS)
    histG[(size_t)i * NBB + blockIdx.x] = hist[i];
}

// ---------------------------------------------------------------------------
// Pass 2a: one wave per bin — exclusive prefix across blocks, emit totals.
__global__ __launch_bounds__(256) void k_scanA(unsigned* __restrict__ histG,
                                               unsigned* __restrict__ binTot,
                                               int nbins) {
  const int w = threadIdx.x >> 6, lane = threadIdx.x & 63;
  const int b = blockIdx.x * 4 + w;
  if (b >= nbins) return;
  unsigned* row = histG + (size_t)b * NBB;
  unsigned carry = 0u;
  for (int c = 0; c < NBB; c += 64) {
    unsigned v = row[c + lane];
    unsigned incl = v;
#pragma unroll
    for (int o = 1; o < 64; o <<= 1) {
      unsigned x = __shfl_up(incl, o);
      if (lane >= o) incl += x;
    }
    row[c + lane] = incl - v + carry;
    carry += __shfl(incl, 63);
  }
  if (lane == 0) binTot[b] = carry;
}

// Pass 2b: single block — exclusive scan of bin totals -> offsB.
__global__ __launch_bounds__(256) void k_scanB(const unsigned* __restrict__ binTot,
                                               unsigned* __restrict__ offsB,
                                               int nbins, long long ET) {
  __shared__ unsigned sh[MAXBINS];
  const int t = threadIdx.x;
  for (int i = t; i < MAXBINS; i += 256) sh[i] = (i < nbins) ? binTot[i] : 0u;
  __syncthreads();
  for (int off = 1; off < MAXBINS; off <<= 1) {
    unsigned v[MAXBINS / 256];
#pragma unroll
    for (int k = 0; k < MAXBINS / 256; ++k) {
      int i = t + k * 256;
      v[k] = (i >= off) ? sh[i - off] : 0u;
    }
    __syncthreads();
#pragma unroll
    for (int k = 0; k < MAXBINS / 256; ++k) sh[t + k * 256] += v[k];
    __syncthreads();
  }
  for (int i = t; i < nbins; i += 256) offsB[i] = (i == 0) ? 0u : sh[i - 1];
  if (t == 0) offsB[nbins] = (unsigned)ET;
}

// ---------------------------------------------------------------------------
// Pass 3: scatter packed records src|(dlocal<<20) into per-(block,bin)
// sequential runs. 1024 threads/block; per-block inline dtype detect.
__global__ __launch_bounds__(TBS) void k_binscat(
    const void* __restrict__ eip, const void* __restrict__ ein,
    const unsigned* __restrict__ histG, const unsigned* __restrict__ offsB,
    unsigned* __restrict__ binned, int Ep, int En, int NBF, long long chunk) {
  __shared__ unsigned cur[MAXBINS];
  __shared__ unsigned shflag;
  const int nbins = 2 * NBF;
  for (int i = threadIdx.x; i < nbins; i += TBS)
    cur[i] = histG[(size_t)i * NBB + blockIdx.x] + offsB[i];
  const bool is64 = detect_is64((const unsigned*)eip, 2 * Ep, &shflag,
                                threadIdx.x, TBS);
  const long long ET = (long long)Ep + En;
  long long beg = (long long)blockIdx.x * chunk;
  long long end = beg + chunk;
  if (end > ET) end = ET;
  for (long long e = beg + threadIdx.x; e < end; e += TBS) {
    int seg = e >= Ep;
    long long ee = seg ? e - Ep : e;
    const void* ei = seg ? ein : eip;
    long long Ecur = seg ? En : Ep;
    int s, d;
    if (is64) {
      const long long* p = (const long long*)ei;
      s = (int)p[ee]; d = (int)p[Ecur + ee];
    } else {
      const int* p = (const int*)ei;
      s = p[ee]; d = p[Ecur + ee];
    }
    unsigned pos = atomicAdd(&cur[seg * NBF + (d >> 7)], 1u);
    binned[pos] = (unsigned)s | ((unsigned)(d & 127) << 20);
  }
}

// ---------------------------------------------------------------------------
// Pass 4: one block per bin — counting-sort by dlocal -> per-node CSR,
// offs + dinv. 512 threads; BOTH segments processed in one pass structure
// (256 LDS counters, [seg*128+dlocal]) — halves barrier count vs 2 passes.
__global__ __launch_bounds__(512) void k_binsort(
    const unsigned* __restrict__ binned, const unsigned* __restrict__ offsB,
    unsigned* __restrict__ csr, unsigned* __restrict__ offsp,
    unsigned* __restrict__ offsn, float* __restrict__ dinvp,
    float* __restrict__ dinvn, int N, int NBF) {
  __shared__ unsigned cnt[2 * RPB], sc[2 * RPB], cur[2 * RPB];
  const int t = threadIdx.x;
  const int b = blockIdx.x;
  const unsigned sb0 = offsB[b],       se0 = offsB[b + 1];
  const unsigned sb1 = offsB[NBF + b], se1 = offsB[NBF + b + 1];
  if (t < 2 * RPB) cnt[t] = 0u;
  __syncthreads();
  for (unsigned i = sb0 + t; i < se0; i += 512)
    atomicAdd(&cnt[binned[i] >> 20], 1u);
  for (unsigned i = sb1 + t; i < se1; i += 512)
    atomicAdd(&cnt[RPB + (binned[i] >> 20)], 1u);
  __syncthreads();
  if (t < 2 * RPB) sc[t] = cnt[t];
  __syncthreads();
  // Hillis-Steele over two independent 128-wide halves (t<128 and 128<=t<256).
#pragma unroll
  for (int o = 1; o < RPB; o <<= 1) {
    unsigned v = 0u;
    if (t < 2 * RPB && (t & (RPB - 1)) >= o) v = sc[t - o];
    __syncthreads();
    if (t < 2 * RPB) sc[t] += v;
    __syncthreads();
  }
  if (t < 2 * RPB) {
    unsigned excl = sc[t] - cnt[t];
    int seg = t >> 7;
    cur[t] = (seg ? sb1 : sb0) + excl;
    int g = b * RPB + (t & (RPB - 1));
    if (g < N) {
      if (seg == 0) {
        offsp[g] = sb0 + excl;
        dinvp[g] = rsqrtf((float)cnt[t] + 1.0f);
      } else {
        offsn[g] = sb1 + excl;
        dinvn[g] = rsqrtf((float)cnt[t] + 1.0f);
      }
    }
  }
  __syncthreads();
  for (unsigned i = sb0 + t; i < se0; i += 512) {
    unsigned w = binned[i];
    unsigned p = atomicAdd(&cur[w >> 20], 1u);
    csr[p] = w & 0xFFFFFu;
  }
  for (unsigned i = sb1 + t; i < se1; i += 512) {
    unsigned w = binned[i];
    unsigned p = atomicAdd(&cur[RPB + (w >> 20)], 1u);
    csr[p] = w & 0xFFFFFu;
  }
  if (b == 0 && t == 0) {
    offsp[N] = offsB[NBF];
    offsn[N] = offsB[2 * NBF];
  }
}

// ---------------------------------------------------------------------------
// Fused LayerNorm + dual GEMM via MFMA (bf16 in, fp32 acc), epilogue scales by
// dinv[row], stores bf16. Block = 256 threads = 4 waves, 64 rows.
__global__ __launch_bounds__(256) void k_ln_gemm(
    const float* __restrict__ h, const float* __restrict__ gamma,
    const float* __restrict__ beta, const unsigned short* __restrict__ Mbt,
    const float* __restrict__ dinvp, const float* __restrict__ dinvn,
    unsigned short* __restrict__ yp, unsigned short* __restrict__ yn, int N) {
  __shared__ __align__(16) unsigned short Abf[64][72];
  __shared__ __align__(16) unsigned short Bt[128][72];
  const int t = threadIdx.x;
  const int r0 = blockIdx.x * 64;

#pragma unroll
  for (int i = 0; i < 4; ++i) {
    int f = i * 256 + t;
    int n = f >> 3, c8 = f & 7;
    *(uint4*)(&Bt[n][c8 * 8]) = ((const uint4*)Mbt)[f];
  }

  const int r = t >> 2, p = t & 3;
  float4 va, vb, vc, vd;
  if (r0 + r < N) {
    const float4* hp = (const float4*)(h + (size_t)(r0 + r) * 64 + p * 16);
    va = hp[0]; vb = hp[1]; vc = hp[2]; vd = hp[3];
  } else {
    va = vb = vc = vd = make_float4(0.f, 0.f, 0.f, 0.f);
  }
  float s  = (va.x + va.y + va.z + va.w) + (vb.x + vb.y + vb.z + vb.w) +
             (vc.x + vc.y + vc.z + vc.w) + (vd.x + vd.y + vd.z + vd.w);
  float ss = (va.x*va.x + va.y*va.y + va.z*va.z + va.w*va.w) +
             (vb.x*vb.x + vb.y*vb.y + vb.z*vb.z + vb.w*vb.w) +
             (vc.x*vc.x + vc.y*vc.y + vc.z*vc.z + vc.w*vc.w) +
             (vd.x*vd.x + vd.y*vd.y + vd.z*vd.z + vd.w*vd.w);
  s  += __shfl_xor(s, 1);  ss += __shfl_xor(ss, 1);
  s  += __shfl_xor(s, 2);  ss += __shfl_xor(ss, 2);
  float mu = s * (1.f / 64.f);
  float var = ss * (1.f / 64.f) - mu * mu;
  float rstd = rsqrtf(var + 1e-5f);
  {
    const float4* g4 = (const float4*)(gamma + p * 16);
    const float4* b4 = (const float4*)(beta + p * 16);
    float4 g0 = g4[0], g1 = g4[1], g2 = g4[2], g3 = g4[3];
    float4 e0 = b4[0], e1 = b4[1], e2 = b4[2], e3 = b4[3];
#define LNV(v, g, e) ((v - mu) * rstd * g + e)
    unsigned w0 = pk2(LNV(va.x, g0.x, e0.x), LNV(va.y, g0.y, e0.y));
    unsigned w1 = pk2(LNV(va.z, g0.z, e0.z), LNV(va.w, g0.w, e0.w));
    unsigned w2 = pk2(LNV(vb.x, g1.x, e1.x), LNV(vb.y, g1.y, e1.y));
    unsigned w3 = pk2(LNV(vb.z, g1.z, e1.z), LNV(vb.w, g1.w, e1.w));
    unsigned w4 = pk2(LNV(vc.x, g2.x, e2.x), LNV(vc.y, g2.y, e2.y));
    unsigned w5 = pk2(LNV(vc.z, g2.z, e2.z), LNV(vc.w, g2.w, e2.w));
    unsigned w6 = pk2(LNV(vd.x, g3.x, e3.x), LNV(vd.y, g3.y, e3.y));
    unsigned w7 = pk2(LNV(vd.z, g3.z, e3.z), LNV(vd.w, g3.w, e3.w));
#undef LNV
    *(uint4*)(&Abf[r][p * 16]) = make_uint4(w0, w1, w2, w3);
    *(uint4*)(&Abf[r][p * 16 + 8]) = make_uint4(w4, w5, w6, w7);
  }
  __syncthreads();

  const int w = t >> 6, lane = t & 63;
  const int mrow = lane & 15, grp = lane >> 4;
  bf16x8 a0 = *(const bf16x8*)(&Abf[w * 16 + mrow][grp * 8]);
  bf16x8 a1 = *(const bf16x8*)(&Abf[w * 16 + mrow][32 + grp * 8]);
  float sp[4], sn[4];
#pragma unroll
  for (int reg = 0; reg < 4; ++reg) {
    int grow = r0 + w * 16 + grp * 4 + reg;
    sp[reg] = (grow < N) ? dinvp[grow] : 0.f;
    sn[reg] = (grow < N) ? dinvn[grow] : 0.f;
  }
#pragma unroll
  for (int ct = 0; ct < 8; ++ct) {
    const int n = ct * 16 + mrow;
    bf16x8 b0 = *(const bf16x8*)(&Bt[n][grp * 8]);
    bf16x8 b1 = *(const bf16x8*)(&Bt[n][32 + grp * 8]);
    f32x4 acc = {0.f, 0.f, 0.f, 0.f};
    acc = __builtin_amdgcn_mfma_f32_16x16x32_bf16(a0, b0, acc, 0, 0, 0);
    acc = __builtin_amdgcn_mfma_f32_16x16x32_bf16(a1, b1, acc, 0, 0, 0);
#pragma unroll
    for (int reg = 0; reg < 4; ++reg) {
      int grow = r0 + w * 16 + grp * 4 + reg;
      if (grow < N) {
        if (ct < 4)
          yp[(size_t)grow * 64 + ct * 16 + mrow] = f2bf(sp[reg] * acc[reg]);
        else
          yn[(size_t)grow * 64 + (ct - 4) * 16 + mrow] = f2bf(sn[reg] * acc[reg]);
      }
    }
  }
}

// ---------------------------------------------------------------------------
// Gather (round-9 proven form): one wave per dst node, FOUR 16-lane groups,
// uint2/lane, 2-deep unroll -> 8 rows in flight. All __shfl execute
// wave-uniformly with clamped source index (ds_bpermute from EXEC-inactive
// source lane is undefined); only loads/accumulates are predicated.
__global__ __launch_bounds__(256) void k_gather(
    const unsigned* __restrict__ offsp, const unsigned* __restrict__ offsn,
    const unsigned* __restrict__ csr, const float* __restrict__ dinvp,
    const float* __restrict__ dinvn, const unsigned short* __restrict__ yp,
    const unsigned short* __restrict__ yn, const float* __restrict__ cvec,
    float* __restrict__ out, int N) {
  const int lane = threadIdx.x & 63;
  const int grp = lane >> 4;
  const int lc = lane & 15;
  const int d = (int)(((long long)blockIdx.x * 256 + threadIdx.x) >> 6);
  if (d >= N) return;

  float4 ap = make_float4(0.f, 0.f, 0.f, 0.f);
  float4 an = make_float4(0.f, 0.f, 0.f, 0.f);

#define ACC4(ACC, U)                                                         \
  ACC.x += bf2f((unsigned short)(U.x & 0xFFFFu));                            \
  ACC.y += bf2f((unsigned short)(U.x >> 16));                                \
  ACC.z += bf2f((unsigned short)(U.y & 0xFFFFu));                            \
  ACC.w += bf2f((unsigned short)(U.y >> 16));

#define GATHER_SEG(OFFS, Y, ACC)                                             \
  {                                                                          \
    unsigned beg = OFFS[d], end = OFFS[d + 1];                               \
    for (unsigned base = beg; base < end; base += 64u) {                     \
      int m = (int)min(64u, end - base);                                     \
      int idx = (base + (unsigned)lane < end) ? (int)csr[base + lane] : 0;   \
      int j = 0;                                                             \
      for (; j + 7 < m; j += 8) {                                            \
        int s0 = __shfl(idx, j + grp);                                       \
        int s1 = __shfl(idx, j + 4 + grp);                                   \
        uint2 u0 = *(const uint2*)(Y + (size_t)s0 * 64 + 4 * lc);            \
        uint2 u1 = *(const uint2*)(Y + (size_t)s1 * 64 + 4 * lc);            \
        ACC4(ACC, u0)                                                        \
        ACC4(ACC, u1)                                                        \
      }                                                                      \
      for (; j < m; j += 4) {                                                \
        int e = j + grp;                                                     \
        int es = (e < m) ? e : (m - 1);  /* clamp: source lane stays valid */\
        int s0 = __shfl(idx, es);        /* executed by ALL lanes */         \
        if (e < m) {                                                         \
          uint2 u0 = *(const uint2*)(Y + (size_t)s0 * 64 + 4 * lc);          \
          ACC4(ACC, u0)                                                      \
        }                                                                    \
      }                                                                      \
    }                                                                        \
  }

  GATHER_SEG(offsp, yp, ap)
  GATHER_SEG(offsn, yn, an)
#undef GATHER_SEG

  ap.x += __shfl_xor(ap.x, 16); ap.y += __shfl_xor(ap.y, 16);
  ap.z += __shfl_xor(ap.z, 16); ap.w += __shfl_xor(ap.w, 16);
  an.x += __shfl_xor(an.x, 16); an.y += __shfl_xor(an.y, 16);
  an.z += __shfl_xor(an.z, 16); an.w += __shfl_xor(an.w, 16);
  ap.x += __shfl_xor(ap.x, 32); ap.y += __shfl_xor(ap.y, 32);
  ap.z += __shfl_xor(ap.z, 32); ap.w += __shfl_xor(ap.w, 32);
  an.x += __shfl_xor(an.x, 32); an.y += __shfl_xor(an.y, 32);
  an.z += __shfl_xor(an.z, 32); an.w += __shfl_xor(an.w, 32);

  if (lane < 16) {
    uint2 up = *(const uint2*)(yp + (size_t)d * 64 + 4 * lc);
    uint2 un = *(const uint2*)(yn + (size_t)d * 64 + 4 * lc);
    ap.x += bf2f((unsigned short)(up.x & 0xFFFFu));
    ap.y += bf2f((unsigned short)(up.x >> 16));
    ap.z += bf2f((unsigned short)(up.y & 0xFFFFu));
    ap.w += bf2f((unsigned short)(up.y >> 16));
    an.x += bf2f((unsigned short)(un.x & 0xFFFFu));
    an.y += bf2f((unsigned short)(un.x >> 16));
    an.z += bf2f((unsigned short)(un.y & 0xFFFFu));
    an.w += bf2f((unsigned short)(un.y >> 16));
    float dp = dinvp[d], dn = dinvn[d];
    float4 cc = *(const float4*)(cvec + 4 * lc);
    float4 v;
    v.x = fminf(fmaxf(cc.x + dp * ap.x + dn * an.x, -50.f), 50.f);
    v.y = fminf(fmaxf(cc.y + dp * ap.y + dn * an.y, -50.f), 50.f);
    v.z = fminf(fmaxf(cc.z + dp * ap.z + dn * an.z, -50.f), 50.f);
    v.w = fminf(fmaxf(cc.w + dp * ap.w + dn * an.w, -50.f), 50.f);
    *(float4*)(out + (size_t)d * 64 + 4 * lc) = v;
  }
#undef ACC4
}

// ---------------------------------------------------------------------------
// Fallback path (atomic scatter), bf16 y pre-scaled by dinv[src].
__global__ __launch_bounds__(256) void k_deg(const void* __restrict__ ei,
                                             const unsigned* __restrict__ flag,
                                             float* __restrict__ deg, int E) {
  int e = blockIdx.x * 256 + threadIdx.x;
  if (e >= E) return;
  long long d;
  if (*flag) d = ((const long long*)ei)[(long long)E + e];
  else       d = (long long)((const int*)ei)[(long long)E + e];
  atomicAdd(&deg[(int)d], 1.0f);
}

__global__ __launch_bounds__(256) void k_dinv(float* __restrict__ degp,
                                              float* __restrict__ degn, int N) {
  int i = blockIdx.x * 256 + threadIdx.x;
  if (i < N) {
    degp[i] = rsqrtf(degp[i] + 1.0f);
    degn[i] = rsqrtf(degn[i] + 1.0f);
  }
}

__global__ __launch_bounds__(256) void k_init_out(
    const unsigned short* __restrict__ yp, const unsigned short* __restrict__ yn,
    const float* __restrict__ dinvp, const float* __restrict__ dinvn,
    const float* __restrict__ cvec, float* __restrict__ out, long long n) {
  long long i = (long long)blockIdx.x * 256 + threadIdx.x;
  if (i >= n) return;
  int row = (int)(i >> 6), col = (int)(i & 63);
  out[i] = cvec[col] + dinvp[row] * bf2f(yp[i]) + dinvn[row] * bf2f(yn[i]);
}

__global__ __launch_bounds__(256) void k_scatter(
    const void* __restrict__ ei, const unsigned* __restrict__ flag,
    const float* __restrict__ dinv, const unsigned short* __restrict__ y,
    float* __restrict__ out, int E) {
  const int lane = threadIdx.x & 63;
  long long e = ((long long)blockIdx.x * 256 + threadIdx.x) >> 6;
  if (e >= E) return;
  long long s, d;
  if (*flag) {
    const long long* p = (const long long*)ei;
    s = p[e]; d = p[E + e];
  } else {
    const int* p = (const int*)ei;
    s = (long long)p[e]; d = (long long)p[E + e];
  }
  float v = dinv[(int)d] * bf2f(y[s * 64 + lane]);
  atomicAdd(out + d * 64 + lane, v);
}

__global__ __launch_bounds__(256) void k_clip(float4* __restrict__ out, int n4) {
  int i = blockIdx.x * 256 + threadIdx.x;
  if (i >= n4) return;
  float4 v = out[i];
  v.x = fminf(fmaxf(v.x, -50.f), 50.f);
  v.y = fminf(fmaxf(v.y, -50.f), 50.f);
  v.z = fminf(fmaxf(v.z, -50.f), 50.f);
  v.w = fminf(fmaxf(v.w, -50.f), 50.f);
  out[i] = v;
}

// ---------------------------------------------------------------------------
extern "C" void kernel_launch(void* const* d_in, const int* in_sizes, int n_in,
                              void* d_out, int out_size, void* d_ws, size_t ws_size,
                              hipStream_t stream) {
  const float* h      = (const float*)d_in[1];
  const void*  ei_pos = d_in[2];
  const void*  ei_neg = d_in[3];
  const float* gamma  = (const float*)d_in[4];
  const float* beta   = (const float*)d_in[5];
  const float* W_pos  = (const float*)d_in[6];
  const float* b_pos  = (const float*)d_in[7];
  const float* W_neg  = (const float*)d_in[8];
  const float* b_neg  = (const float*)d_in[9];
  const float* Wp     = (const float*)d_in[10];
  const float* bp     = (const float*)d_in[11];
  const float* Wn     = (const float*)d_in[12];
  const float* bn     = (const float*)d_in[13];
  float* out = (float*)d_out;

  const int N = in_sizes[1] / HID;
  const int Ep = in_sizes[2] / 2;
  const int En = in_sizes[3] / 2;
  const int NBF = (N + RPB - 1) / RPB;
  const int nbins = 2 * NBF;
  const long long ET = (long long)Ep + En;

  float* ws = (float*)d_ws;
  size_t off = 0;
  auto alloc = [&](size_t nf) {
    float* p = ws + off;
    off = (off + nf + 63) & ~(size_t)63;
    return p;
  };
  // Common arrays.
  unsigned short* y_pos = (unsigned short*)alloc((size_t)N * HID / 2);
  unsigned short* y_neg = (unsigned short*)alloc((size_t)N * HID / 2);
  float* dinvp = alloc(N);
  float* dinvn = alloc(N);
  unsigned short* Mbt = (unsigned short*)alloc(128 * 64 / 2);
  float* cvec  = alloc(64);
  unsigned* flag = (unsigned*)alloc(64);
  // Fast-path arrays.
  unsigned* histG  = (unsigned*)alloc((size_t)nbins * NBB);
  unsigned* binTot = (unsigned*)alloc(MAXBINS);
  unsigned* offsB  = (unsigned*)alloc(nbins + 1);
  unsigned* offsp  = (unsigned*)alloc(N + 1);
  unsigned* offsn  = (unsigned*)alloc(N + 1);
  unsigned* binned = (unsigned*)alloc((size_t)ET);
  unsigned* csr    = (unsigned*)alloc((size_t)ET);
  const bool fast = (off * sizeof(float) <= ws_size) && (nbins <= MAXBINS) &&
                    (N < (1 << 20));

  if (fast) {
    // chunk: multiple of TBS so per-block stride loops stay aligned.
    const long long chunk =
        ((ET + (long long)NBB * TBS - 1) / ((long long)NBB * TBS)) * TBS;
    k_hist_prep<<<NBB + 4, TBS, 0, stream>>>(
        ei_pos, ei_neg, histG, Ep, En, NBF, chunk,
        W_pos, W_neg, Wp, Wn, b_pos, b_neg, bp, bn, Mbt, cvec);
    k_scanA<<<(nbins + 3) / 4, 256, 0, stream>>>(histG, binTot, nbins);
    k_scanB<<<1, 256, 0, stream>>>(binTot, offsB, nbins, ET);
    k_binscat<<<NBB, TBS, 0, stream>>>(ei_pos, ei_neg, histG, offsB, binned,
                                       Ep, En, NBF, chunk);
    k_binsort<<<NBF, 512, 0, stream>>>(binned, offsB, csr, offsp, offsn,
                                       dinvp, dinvn, N, NBF);
    k_ln_gemm<<<(N + 63) / 64, 256, 0, stream>>>(h, gamma, beta, Mbt, dinvp, dinvn,
                                                 y_pos, y_neg, N);
    const long long gthreads = (long long)N * 64;
    k_gather<<<(int)((gthreads + 255) / 256), 256, 0, stream>>>(
        offsp, offsn, csr, dinvp, dinvn, y_pos, y_neg, cvec, out, N);
  } else {
    k_prep<<<17, 256, 0, stream>>>(W_pos, W_neg, Wp, Wn, b_pos, b_neg, bp, bn,
                                   Mbt, cvec, (const unsigned*)ei_pos, flag, 2 * Ep);
    hipMemsetAsync(dinvp, 0, sizeof(float) * N, stream);
    hipMemsetAsync(dinvn, 0, sizeof(float) * N, stream);
    k_deg<<<(Ep + 255) / 256, 256, 0, stream>>>(ei_pos, flag, dinvp, Ep);
    k_deg<<<(En + 255) / 256, 256, 0, stream>>>(ei_neg, flag, dinvn, En);
    k_dinv<<<(N + 255) / 256, 256, 0, stream>>>(dinvp, dinvn, N);
    k_ln_gemm<<<(N + 63) / 64, 256, 0, stream>>>(h, gamma, beta, Mbt, dinvp, dinvn,
                                                 y_pos, y_neg, N);
    const long long n = (long long)N * 64;
    k_init_out<<<(int)((n + 255) / 256), 256, 0, stream>>>(y_pos, y_neg, dinvp, dinvn,
                                                           cvec, out, n);
    const long long st = (long long)Ep * 64;
    k_scatter<<<(int)((st + 255) / 256), 256, 0, stream>>>(ei_pos, flag, dinvp, y_pos,
                                                           out, Ep);
    const long long stn = (long long)En * 64;
    k_scatter<<<(int)((stn + 255) / 256), 256, 0, stream>>>(ei_neg, flag, dinvn, y_neg,
                                                            out, En);
    const int n4 = N * 16;
    k_clip<<<(n4 + 255) / 256, 256, 0, stream>>>((float4*)out, n4);
  }
}